// Round 1
// baseline (458.384 us; speedup 1.0000x reference)
//
#include <hip/hip_runtime.h>

#define T_SEQ 2000
#define N_UTT 64
#define DQ 256
#define NTOK 10
#define NH 8
#define DS 32

typedef float f32x4 __attribute__((ext_vector_type(4)));
typedef short s16x8 __attribute__((ext_vector_type(8)));

__device__ __forceinline__ unsigned short f2bf(float f){
    unsigned int u = __float_as_uint(f);
    u += 0x7FFFu + ((u >> 16) & 1u);     // round-to-nearest-even
    return (unsigned short)(u >> 16);
}
__device__ __forceinline__ float bf2f(unsigned short h){
    return __uint_as_float(((unsigned int)h) << 16);
}

// Prep: Wq -> bf16 (row-major [u][q]), and k/v = tanh(embed) @ Wk^T / Wv^T in fp32.
__global__ __launch_bounds__(256) void prep_kernel(
    const float* __restrict__ embed, const float* __restrict__ Wq,
    const float* __restrict__ Wk, const float* __restrict__ Wv,
    unsigned short* __restrict__ WqB, float* __restrict__ khd, float* __restrict__ vhd)
{
    const int b = blockIdx.x, t = threadIdx.x;
    if (b < 256){
        const int i = b*256 + t;
        WqB[i] = f2bf(Wq[i]);
    } else {
        // t indexes u in [0,256)
        for (int tok = 0; tok < NTOK; ++tok){
            float ka = 0.f, va = 0.f;
            #pragma unroll
            for (int d = 0; d < DS; ++d){
                const float kd = tanhf(embed[tok*DS + d]);
                ka += kd * Wk[t*DS + d];
                va += kd * Wv[t*DS + d];
            }
            khd[tok*256 + t] = ka;   // [tok][u], u = h*32 + d
            vhd[tok*256 + t] = va;
        }
    }
}

#define XS_STRIDE 264   // bf16 elems per row (256 + 8 pad); 528B = 16B-aligned rows
#define QS_STRIDE 260   // fp32 elems per row; 1040B = 16B-aligned rows, bank-shift 4

__global__ __launch_bounds__(256, 3) void main_kernel(
    const float* __restrict__ inputs, const int* __restrict__ pidx,
    const float* __restrict__ pos_table, const unsigned short* __restrict__ WqB,
    const float* __restrict__ khd, const float* __restrict__ vhd,
    float* __restrict__ outp, float* __restrict__ scores)
{
    __shared__ unsigned short xs_hi[16*XS_STRIDE];  // 8448 B
    __shared__ unsigned short xs_lo[16*XS_STRIDE];  // 8448 B
    __shared__ float qs[16*QS_STRIDE];              // 16640 B
    __shared__ float khL[NTOK*256];                 // 10240 B
    __shared__ float vhL[NTOK*256];                 // 10240 B  -> total 54016 B, 3 blocks/CU

    const int tid = threadIdx.x;
    const int m0 = blockIdx.x * 16;      // flat row tile; 2000 % 16 == 0 so single n
    const int n  = m0 / T_SEQ;
    const int t0 = m0 % T_SEQ;

    // stage k/v heads into LDS (coalesced; reused by all rows of the tile)
    #pragma unroll
    for (int i = 0; i < NTOK; ++i){
        khL[i*256 + tid] = khd[i*256 + tid];
        vhL[i*256 + tid] = vhd[i*256 + tid];
    }

    // stage x = inputs + pos_table[idx] as bf16 hi/lo split
    {
        const int rsub = tid >> 6;          // 0..3
        const int c    = (tid & 63) * 4;    // 0..252
        #pragma unroll
        for (int p = 0; p < 4; ++p){
            const int r   = p*4 + rsub;
            const int row = m0 + r;
            const int idx = pidx[row];
            const float4 xi = *(const float4*)(inputs    + (size_t)row*DQ + c);
            const float4 pe = *(const float4*)(pos_table + (size_t)idx*DQ + c);
            float xv[4] = {xi.x+pe.x, xi.y+pe.y, xi.z+pe.z, xi.w+pe.w};
            unsigned short hs[4], ls[4];
            #pragma unroll
            for (int j = 0; j < 4; ++j){
                hs[j] = f2bf(xv[j]);
                ls[j] = f2bf(xv[j] - bf2f(hs[j]));
            }
            *(uint2*)&xs_hi[r*XS_STRIDE + c] =
                make_uint2(hs[0] | ((unsigned)hs[1] << 16), hs[2] | ((unsigned)hs[3] << 16));
            *(uint2*)&xs_lo[r*XS_STRIDE + c] =
                make_uint2(ls[0] | ((unsigned)ls[1] << 16), ls[2] | ((unsigned)ls[3] << 16));
        }
    }
    __syncthreads();

    // GEMM: q[16 rows][256 u] = x @ Wq^T via mfma_f32_16x16x32_bf16, split-A for accuracy.
    {
        const int wave = tid >> 6;
        const int lane = tid & 63;
        const int lrow = lane & 15;     // A: m index / B: n index
        const int quad = lane >> 4;     // A,B: k = quad*8 + j ; D: row = quad*4 + reg
        const int u0w  = wave * 64;

        s16x8 ah[8], al[8];
        #pragma unroll
        for (int kt = 0; kt < 8; ++kt){
            ah[kt] = *(const s16x8*)&xs_hi[lrow*XS_STRIDE + kt*32 + quad*8];
            al[kt] = *(const s16x8*)&xs_lo[lrow*XS_STRIDE + kt*32 + quad*8];
        }
        f32x4 acc[4] = {};   // 4 col-tiles of 16 u each
        #pragma unroll
        for (int kt = 0; kt < 8; ++kt){
            s16x8 bfr[4];
            #pragma unroll
            for (int ct = 0; ct < 4; ++ct){
                const int u = u0w + ct*16 + lrow;
                // B[k][u] = Wq[u][k]; lane reads 8 contiguous k at row u -> 16B load, L2-hot
                bfr[ct] = *(const s16x8*)(WqB + u*256 + kt*32 + quad*8);
            }
            #pragma unroll
            for (int ct = 0; ct < 4; ++ct){
                acc[ct] = __builtin_amdgcn_mfma_f32_16x16x32_bf16(al[kt], bfr[ct], acc[ct], 0,0,0);
                acc[ct] = __builtin_amdgcn_mfma_f32_16x16x32_bf16(ah[kt], bfr[ct], acc[ct], 0,0,0);
            }
        }
        // D layout: row = quad*4+reg, col = lane&15  (verified m89/m91)
        #pragma unroll
        for (int ct = 0; ct < 4; ++ct){
            #pragma unroll
            for (int reg = 0; reg < 4; ++reg){
                qs[(quad*4 + reg)*QS_STRIDE + u0w + ct*16 + lrow] = acc[ct][reg];
            }
        }
    }
    __syncthreads();

    // Attention: one thread per (row, head); 10-token softmax; scores + out.
    if (tid < 128){
        const int r = tid & 15;
        const int h = tid >> 4;
        const int t = t0 + r;

        float q[32];
        #pragma unroll
        for (int d = 0; d < 32; d += 4){
            const float4 v4 = *(const float4*)&qs[r*QS_STRIDE + h*32 + d];
            q[d+0]=v4.x; q[d+1]=v4.y; q[d+2]=v4.z; q[d+3]=v4.w;
        }
        const float scale = 0.17677669529663687f;  // 1/sqrt(32)
        float logit[NTOK];
        float mx = -1e30f;
        #pragma unroll
        for (int k = 0; k < NTOK; ++k){
            const float* kp = &khL[k*256 + h*32];   // broadcast across the 16 r-lanes
            float a0=0.f,a1=0.f,a2=0.f,a3=0.f;
            #pragma unroll
            for (int d = 0; d < 32; d += 4){
                a0 += q[d+0]*kp[d+0];
                a1 += q[d+1]*kp[d+1];
                a2 += q[d+2]*kp[d+2];
                a3 += q[d+3]*kp[d+3];
            }
            logit[k] = ((a0+a1)+(a2+a3))*scale;
            mx = fmaxf(mx, logit[k]);
        }
        float p[NTOK], s = 0.f;
        #pragma unroll
        for (int k = 0; k < NTOK; ++k){ p[k] = __expf(logit[k]-mx); s += p[k]; }
        const float inv = 1.f/s;
        #pragma unroll
        for (int k = 0; k < NTOK; ++k){
            p[k] *= inv;
            // scores[n][h*10+k][t]
            scores[(n*(NH*NTOK) + h*NTOK + k)*T_SEQ + t] = p[k];
        }
        #pragma unroll
        for (int d = 0; d < 32; d += 4){
            float4 o = make_float4(0.f,0.f,0.f,0.f);
            #pragma unroll
            for (int k = 0; k < NTOK; ++k){
                const float4 vv = *(const float4*)&vhL[k*256 + h*32 + d];
                o.x += p[k]*vv.x; o.y += p[k]*vv.y; o.z += p[k]*vv.z; o.w += p[k]*vv.w;
            }
            *(float4*)(outp + (size_t)(m0 + r)*DQ + h*32 + d) = o;
        }
    }
}

extern "C" void kernel_launch(void* const* d_in, const int* in_sizes, int n_in,
                              void* d_out, int out_size, void* d_ws, size_t ws_size,
                              hipStream_t stream)
{
    const float* inputs    = (const float*)d_in[0];
    const int*   pidx      = (const int*)d_in[1];   // integer input -> int32 per harness
    const float* embed     = (const float*)d_in[2];
    const float* Wq        = (const float*)d_in[3];
    const float* Wk        = (const float*)d_in[4];
    const float* Wv        = (const float*)d_in[5];
    const float* pos_table = (const float*)d_in[6];

    float* outp   = (float*)d_out;                          // [64*2000*256]
    float* scores = outp + (size_t)N_UTT*T_SEQ*DQ;          // [64*80*2000]

    unsigned short* WqB = (unsigned short*)d_ws;                         // 128 KiB
    float* khd = (float*)((char*)d_ws + 256*256*sizeof(unsigned short)); // 10*256 f32
    float* vhd = khd + NTOK*256;

    prep_kernel<<<257, 256, 0, stream>>>(embed, Wq, Wk, Wv, WqB, khd, vhd);
    main_kernel<<<8000, 256, 0, stream>>>(inputs, pidx, pos_table, WqB, khd, vhd,
                                          outp, scores);
}